// Round 2
// baseline (938.671 us; speedup 1.0000x reference)
//
#include <hip/hip_runtime.h>
#include <hip/hip_bf16.h>

#define N_NODES 30000
#define N_EDGES 120000
#define NGRAPH  512
#define N2      15000
#define N3      7500
#define NC      10

#define T1N 64                          // dest nodes per tile, conv1
#define NT1 ((N_NODES + T1N - 1) / T1N) // 469
#define T2N 16                          // pooled dest nodes per tile, conv2
#define NT2 ((N2 + T2N - 1) / T2N)      // 938
#define KI  832                         // 26*32 (25 t-rows + bias row) x 32 inputs

typedef __hip_bfloat16 bf16;

__device__ __forceinline__ float lo(const float* p, int i) { return p[i]; }
__device__ __forceinline__ float lo(const bf16* p, int i) { return __bfloat162float(p[i]); }
__device__ __forceinline__ void sto(float* p, int i, float v) { p[i] = v; }
__device__ __forceinline__ void sto(bf16* p, int i, float v) { p[i] = __float2bfloat16(v); }
__device__ __forceinline__ float elu(float x) { return x > 0.f ? x : expm1f(x); }
template <typename T> __host__ __device__ constexpr int want_flag() { return sizeof(T) == 4 ? 1 : 0; }

// ---------------- workspace layout (float offsets) ----------------
// zero region (memset each call):
#define MV_OFF   0        // maxv (uint bits): 1
#define GS_OFF   1        // gsum: G*64 = 32768
#define GC_OFF   32769    // gcnt: G = 512
#define DEG1_OFF 33281    // conv1 dest-tile degree (int): NT1 = 469
#define DEG2_OFF 33750    // conv2 dest-tile degree (int): NT2 = 938
#define ZERO_FLOATS 34688
// non-zero region:
#define X2_OFF   34688    // x2:   N2*32 = 480000
#define P2_OFF   514688   // pos2: N2*2  = 30000
#define CT_OFF   544688   // cart: E*2   = 240000
#define OFF1_OFF 784688   // conv1 tile offsets (int): NT1+1 = 470
#define CUR1_OFF 785158   // conv1 cursor (int): NT1 = 469
#define ES1_OFF  785627   // conv1 dest-sorted edge ids (int): E = 120000
#define OFF2_OFF 905627   // conv2 tile offsets (int): NT2+1 = 939
#define CUR2_OFF 906566   // conv2 cursor (int): NT2 = 938
#define ES2_OFF  907504   // conv2 dest-sorted edge ids (int): E = 120000
#define H2_OFF   1027504  // h2: N2*64 = 960000
#define FLAG_OFF 1987504  // dtype flag (int)
// total 1987505 floats ~= 7.95 MB

// ---------------- dtype detector: bf16-view of fp32 data shows |v|>1e3 or NaN
__global__ __launch_bounds__(256) void k0_detect(const void* x, const void* ea, int* flag) {
  const bf16* xb = (const bf16*)x;
  const bf16* eb = (const bf16*)ea;
  int tid = threadIdx.x;
  float a = __bfloat162float(xb[tid]);
  float b = __bfloat162float(eb[tid]);
  int bad = (!(fabsf(a) < 1e3f)) || (!(fabsf(b) < 1e3f));  // catches NaN/Inf too
  unsigned long long m = __ballot(bad);
  __shared__ int anyb[4];
  int w = tid >> 6;
  if ((tid & 63) == 0) anyb[w] = (m != 0ULL) ? 1 : 0;
  __syncthreads();
  if (tid == 0) flag[0] = (anyb[0] | anyb[1] | anyb[2] | anyb[3]);
}

// ---------------- CSR-by-dest-tile build (dtype-free)
__global__ __launch_bounds__(256) void kc_deg(const int* __restrict__ ei,
                                              int* __restrict__ deg1, int* __restrict__ deg2) {
  int e = blockIdx.x * 256 + threadIdx.x;
  if (e >= N_EDGES) return;
  int col = ei[N_EDGES + e];
  atomicAdd(deg1 + (col >> 6), 1);                       // conv1: all edges, tile of 64 nodes
  int r2 = ei[e] >> 1, c2 = col >> 1;
  if (r2 != c2) atomicAdd(deg2 + (c2 >> 4), 1);          // conv2: masked out self-pairs
}

__global__ __launch_bounds__(256) void kc_scan(const int* __restrict__ deg,
                                               int* __restrict__ off, int* __restrict__ cur,
                                               int n) {
  __shared__ int buf[256];
  __shared__ int carry_s;
  int tid = threadIdx.x;
  if (tid == 0) carry_s = 0;
  __syncthreads();
  for (int base = 0; base < n; base += 256) {
    int i = base + tid;
    int v = (i < n) ? deg[i] : 0;
    buf[tid] = v;
    __syncthreads();
    for (int s = 1; s < 256; s <<= 1) {
      int tv = (tid >= s) ? buf[tid - s] : 0;
      __syncthreads();
      buf[tid] += tv;
      __syncthreads();
    }
    int excl = carry_s + buf[tid] - v;
    if (i < n) { off[i] = excl; cur[i] = excl; }
    int tot = buf[255];
    __syncthreads();
    if (tid == 0) carry_s += tot;
    __syncthreads();
  }
  if (tid == 0) off[n] = carry_s;
}

__global__ __launch_bounds__(256) void kc_place(const int* __restrict__ ei,
                                                int* __restrict__ cur1, int* __restrict__ es1,
                                                int* __restrict__ cur2, int* __restrict__ es2) {
  int e = blockIdx.x * 256 + threadIdx.x;
  if (e >= N_EDGES) return;
  int col = ei[N_EDGES + e];
  int p = atomicAdd(cur1 + (col >> 6), 1);
  es1[p] = e;
  int r2 = ei[e] >> 1, c2 = col >> 1;
  if (r2 != c2) {
    int q = atomicAdd(cur2 + (c2 >> 4), 1);
    es2[q] = e;
  }
}

// ---------------- conv1 fused: dest-tile LDS aggregation + node update + pair pool
// msg[o] = x[src] * (sum_k t_k w1b[k,o] + b1b[o]); aggr over dest in LDS (no global atomics)
template <typename T>
__global__ __launch_bounds__(256) void k1_tile(
    const int* __restrict__ flag,
    const T* __restrict__ x, const T* __restrict__ ea, const T* __restrict__ pos,
    const int* __restrict__ ei,
    const T* __restrict__ w1a, const T* __restrict__ b1a,
    const T* __restrict__ w1b, const T* __restrict__ b1b,
    const T* __restrict__ root1, const T* __restrict__ bias1,
    const int* __restrict__ off1, const int* __restrict__ es1,
    float* __restrict__ x2, float* __restrict__ pos2) {
  if (flag[0] != want_flag<T>()) return;
  __shared__ float w1a_l[50];
  __shared__ float b1a_l[25];
  __shared__ float w1b_l[800];      // [k*32+o]
  __shared__ float b1b_l[32];
  __shared__ float aggT[64 * 33];   // stride 33: randomizes atomic banks by dest
  __shared__ float cntT[64];
  int tid = threadIdx.x, t = blockIdx.x;
  for (int j = tid; j < 50; j += 256) w1a_l[j] = lo(w1a, j);
  for (int j = tid; j < 25; j += 256) b1a_l[j] = lo(b1a, j);
  for (int j = tid; j < 800; j += 256) w1b_l[j] = lo(w1b, j);
  for (int j = tid; j < 32; j += 256) b1b_l[j] = lo(b1b, j);
  for (int j = tid; j < 64 * 33; j += 256) aggT[j] = 0.f;
  if (tid < 64) cntT[tid] = 0.f;
  __syncthreads();
  int j0 = off1[t], j1 = off1[t + 1];
  int slot = tid >> 2, og = tid & 3;
  for (int j = j0 + slot; j < j1; j += 64) {
    int e = es1[j];
    int src = ei[e];
    int dl = ei[N_EDGES + e] - t * T1N;
    float a0 = lo(ea, 2 * e), a1 = lo(ea, 2 * e + 1);
    float xv = lo(x, src);
    float tk[25];
#pragma unroll
    for (int k = 0; k < 25; ++k)
      tk[k] = fmaxf(a0 * w1a_l[k] + a1 * w1a_l[25 + k] + b1a_l[k], 0.f);
    float* ag = aggT + dl * 33;
#pragma unroll
    for (int i = 0; i < 8; ++i) {
      int o = og * 8 + i;
      float s = b1b_l[o];
#pragma unroll
      for (int k = 0; k < 25; ++k) s += tk[k] * w1b_l[k * 32 + o];
      atomicAdd(ag + o, xv * s);
    }
    if (og == 0) atomicAdd(cntT + dl, 1.f);
  }
  __syncthreads();
  // node update + elu (in place)
  for (int idx = tid; idx < 64 * 32; idx += 256) {
    int nl = idx >> 5, o = idx & 31;
    int n = t * T1N + nl;
    if (n < N_NODES) {
      float c = fmaxf(cntT[nl], 1.f);
      float h = elu(aggT[nl * 33 + o] / c + lo(x, n) * lo(root1, o) + lo(bias1, o));
      aggT[nl * 33 + o] = h;
    }
  }
  __syncthreads();
  // pair max-pool -> x2 ; pos mean-pool -> pos2
  for (int idx = tid; idx < 32 * 32; idx += 256) {
    int pl = idx >> 5, o = idx & 31;
    int m = t * 32 + pl;
    if (m < N2)
      x2[m * 32 + o] = fmaxf(aggT[(2 * pl) * 33 + o], aggT[(2 * pl + 1) * 33 + o]);
  }
  if (tid < 64) {
    int pl = tid >> 1, c = tid & 1;
    int m = t * 32 + pl;
    if (m < N2)
      pos2[m * 2 + c] = 0.5f * (lo(pos, (2 * m) * 2 + c) + lo(pos, (2 * m + 1) * 2 + c));
  }
}

// ---------------- cart + global abs-max (fp32 intermediates only; no dtype dep)
__global__ __launch_bounds__(256) void k3_cart(
    const int* __restrict__ ei, const float* __restrict__ pos2,
    float* __restrict__ cart, unsigned int* __restrict__ maxv) {
  int e = blockIdx.x * 256 + threadIdx.x;
  float m = 0.f;
  if (e < N_EDGES) {
    int r2 = ei[e] >> 1, c2 = ei[N_EDGES + e] >> 1;
    float cx = 0.f, cy = 0.f;
    if (r2 != c2) {
      cx = pos2[2 * c2] - pos2[2 * r2];
      cy = pos2[2 * c2 + 1] - pos2[2 * r2 + 1];
    }
    cart[2 * e] = cx;
    cart[2 * e + 1] = cy;
    m = fmaxf(fabsf(cx), fabsf(cy));
  }
#pragma unroll
  for (int s = 32; s > 0; s >>= 1)
    m = fmaxf(m, __shfl_xor(m, s, 64));
  __shared__ float wm[4];
  int lane = threadIdx.x & 63, wid = threadIdx.x >> 6;
  if (lane == 0) wm[wid] = m;
  __syncthreads();
  if (threadIdx.x == 0) {
    float mm = fmaxf(fmaxf(wm[0], wm[1]), fmaxf(wm[2], wm[3]));
    atomicMax(maxv, __float_as_uint(mm));
  }
}

// ---------------- conv2 fused, dest-side S-factorization.
// S[dst][k,i] = sum_{e->dst} t'_k(e) * x2[src_e, i]  (t'_25 = 1)
// aggr[dst][o] = sum_ki S[dst][ki] * W2[ki][o],  W2[ki<800]=w2b[ki*64+o], else b2b
// h2 = elu(aggr/cnt + x2 @ root2 + bias2)   -- all in one kernel, no global atomics.
template <typename T>
__global__ __launch_bounds__(256, 2) void k4_dest(
    const int* __restrict__ flag,
    const int* __restrict__ ei, const float* __restrict__ cart, const float* __restrict__ maxv_f,
    const float* __restrict__ x2,
    const T* __restrict__ w2a, const T* __restrict__ b2a,
    const T* __restrict__ w2b, const T* __restrict__ b2b,
    const T* __restrict__ root2, const T* __restrict__ bias2,
    const int* __restrict__ off2, const int* __restrict__ es2,
    float* __restrict__ h2) {
  if (flag[0] != want_flag<T>()) return;
  __shared__ float w2a_l[50];
  __shared__ float b2a_l[25];
  __shared__ float S[T2N][KI];        // 53248 B
  __shared__ float cntT[T2N];
  __shared__ float P[4][T2N * 64];    // cross-wave partials, 16384 B
  int tid = threadIdx.x, t = blockIdx.x;
  for (int j = tid; j < 50; j += 256) w2a_l[j] = lo(w2a, j);
  for (int j = tid; j < 25; j += 256) b2a_l[j] = lo(b2a, j);
  for (int j = tid; j < T2N * KI; j += 256) ((float*)S)[j] = 0.f;
  if (tid < T2N) cntT[tid] = 0.f;
  __syncthreads();
  float inv = 0.5f / maxv_f[0];
  int j0 = off2[t], j1 = off2[t + 1];
  int w = tid >> 6, lane = tid & 63;
  int il = lane & 31;                 // input index this lane owns (constant across it)
  // phase 1: accumulate S over this tile's in-edges (one wave per edge)
  for (int j = j0 + w; j < j1; j += 4) {
    int e = es2[j];
    int r2 = ei[e] >> 1;
    int dl = (ei[N_EDGES + e] >> 1) - t * T2N;
    float ax = cart[2 * e] * inv + 0.5f;
    float ay = cart[2 * e + 1] * inv + 0.5f;
    float xval = x2[r2 * 32 + il];
#pragma unroll
    for (int it = 0; it < 13; ++it) {
      int ki = it * 64 + lane;
      int k = ki >> 5;
      float tk = (k < 25) ? fmaxf(ax * w2a_l[k] + ay * w2a_l[25 + k] + b2a_l[k], 0.f) : 1.f;
      atomicAdd(&S[dl][ki], tk * xval);
    }
    if (lane == 0) atomicAdd(&cntT[dl], 1.f);
  }
  __syncthreads();
  // phase 2: contraction, each wave takes a ki-range, lane = output channel o
  float acc[T2N];
#pragma unroll
  for (int nl = 0; nl < T2N; ++nl) acc[nl] = 0.f;
  int kbeg = w * 208, kend = kbeg + 208;
  int ke1 = kend < 800 ? kend : 800;
#pragma unroll 4
  for (int ki = kbeg; ki < ke1; ++ki) {
    float wv = lo(w2b, ki * 64 + lane);
#pragma unroll
    for (int nl = 0; nl < T2N; ++nl) acc[nl] += S[nl][ki] * wv;
  }
  int kb2 = kbeg > 800 ? kbeg : 800;
#pragma unroll 4
  for (int ki = kb2; ki < kend; ++ki) {
    float wv = lo(b2b, (ki - 800) * 64 + lane);
#pragma unroll
    for (int nl = 0; nl < T2N; ++nl) acc[nl] += S[nl][ki] * wv;
  }
#pragma unroll
  for (int nl = 0; nl < T2N; ++nl) P[w][nl * 64 + lane] = acc[nl];
  __syncthreads();
  // phase 3: reduce partials + mean + root2 + bias2 + elu -> h2
  for (int idx = tid; idx < T2N * 64; idx += 256) {
    int nl = idx >> 6, o = idx & 63;
    int n = t * T2N + nl;
    if (n < N2) {
      float s = P[0][idx] + P[1][idx] + P[2][idx] + P[3][idx];
      float r = lo(bias2, o);
      const float* xr = x2 + n * 32;
#pragma unroll 8
      for (int i = 0; i < 32; ++i) r += xr[i] * lo(root2, i * 64 + o);
      h2[n * 64 + o] = elu(s / fmaxf(cntT[nl], 1.f) + r);
    }
  }
}

// ---------------- pair max-pool 2 + per-graph segmented sum (batch sorted -> few atomics)
#define K6CH 16
__global__ __launch_bounds__(256) void k6_pool2(
    const float* __restrict__ h2, const int* __restrict__ batch,
    float* __restrict__ gsum, float* __restrict__ gcnt) {
  int wid = blockIdx.x * 4 + (threadIdx.x >> 6);
  int lane = threadIdx.x & 63;
  int m0 = wid * K6CH;
  if (m0 >= N3) return;
  int m1 = m0 + K6CH < N3 ? m0 + K6CH : N3;
  int bcur = batch[4 * m0];
  float acc = 0.f, cnt = 0.f;
  for (int m = m0; m < m1; ++m) {
    int b = batch[4 * m];
    float v = fmaxf(h2[(2 * m) * 64 + lane], h2[(2 * m + 1) * 64 + lane]);
    if (b != bcur) {
      atomicAdd(gsum + bcur * 64 + lane, acc);
      if (lane == 0) atomicAdd(gcnt + bcur, cnt);
      acc = 0.f; cnt = 0.f; bcur = b;
    }
    acc += v; cnt += 1.f;
  }
  atomicAdd(gsum + bcur * 64 + lane, acc);
  if (lane == 0) atomicAdd(gcnt + bcur, cnt);
}

// ---------------- graph mean -> fc1 -> elu -> fc2 -> log_softmax
template <typename T>
__global__ __launch_bounds__(128) void k7_head(
    const int* __restrict__ flag,
    const float* __restrict__ gsum, const float* __restrict__ gcnt,
    const T* __restrict__ fc1_w, const T* __restrict__ fc1_b,
    const T* __restrict__ fc2_w, const T* __restrict__ fc2_b,
    T* __restrict__ out) {
  if (flag[0] != want_flag<T>()) return;
  __shared__ float gv[64];
  __shared__ float h1s[128];
  __shared__ float zs[NC];
  __shared__ float lse;
  int g = blockIdx.x, tid = threadIdx.x;
  if (tid < 64) gv[tid] = gsum[g * 64 + tid] / fmaxf(gcnt[g], 1.f);
  __syncthreads();
  float a = lo(fc1_b, tid);
#pragma unroll 8
  for (int o = 0; o < 64; ++o) a += gv[o] * lo(fc1_w, o * 128 + tid);
  h1s[tid] = elu(a);
  __syncthreads();
  if (tid < NC) {
    float s = lo(fc2_b, tid);
    for (int j = 0; j < 128; ++j) s += h1s[j] * lo(fc2_w, j * NC + tid);
    zs[tid] = s;
  }
  __syncthreads();
  if (tid == 0) {
    float m = -1e30f;
    for (int c = 0; c < NC; ++c) m = fmaxf(m, zs[c]);
    float s = 0.f;
    for (int c = 0; c < NC; ++c) s += expf(zs[c] - m);
    lse = m + logf(s);
  }
  __syncthreads();
  if (tid < NC) sto(out, g * NC + tid, zs[tid] - lse);
}

template <typename T>
static void run_stages(void* const* d_in, float* ws, hipStream_t stream, int which) {
  const int* ei   = (const int*)d_in[19];
  const int* flag = (const int*)(ws + FLAG_OFF);
  if (which == 1) {
    k1_tile<T><<<NT1, 256, 0, stream>>>(
        flag, (const T*)d_in[0], (const T*)d_in[1], (const T*)d_in[2], ei,
        (const T*)d_in[3], (const T*)d_in[4], (const T*)d_in[5], (const T*)d_in[6],
        (const T*)d_in[7], (const T*)d_in[8],
        (const int*)(ws + OFF1_OFF), (const int*)(ws + ES1_OFF),
        ws + X2_OFF, ws + P2_OFF);
  } else {
    k4_dest<T><<<NT2, 256, 0, stream>>>(
        flag, ei, ws + CT_OFF, ws + MV_OFF, ws + X2_OFF,
        (const T*)d_in[9], (const T*)d_in[10], (const T*)d_in[11], (const T*)d_in[12],
        (const T*)d_in[13], (const T*)d_in[14],
        (const int*)(ws + OFF2_OFF), (const int*)(ws + ES2_OFF),
        ws + H2_OFF);
  }
}

extern "C" void kernel_launch(void* const* d_in, const int* in_sizes, int n_in,
                              void* d_out, int out_size, void* d_ws, size_t ws_size,
                              hipStream_t stream) {
  float* ws = (float*)d_ws;
  const int* flag = (const int*)(ws + FLAG_OFF);
  const int* ei = (const int*)d_in[19];
  const int* batch = (const int*)d_in[20];

  k0_detect<<<1, 256, 0, stream>>>(d_in[0], d_in[1], (int*)(ws + FLAG_OFF));
  hipMemsetAsync(d_ws, 0, (size_t)ZERO_FLOATS * 4, stream);

  // dest-tile CSR builds (dtype-free)
  kc_deg<<<(N_EDGES + 255) / 256, 256, 0, stream>>>(
      ei, (int*)(ws + DEG1_OFF), (int*)(ws + DEG2_OFF));
  kc_scan<<<1, 256, 0, stream>>>((const int*)(ws + DEG1_OFF), (int*)(ws + OFF1_OFF),
                                 (int*)(ws + CUR1_OFF), NT1);
  kc_scan<<<1, 256, 0, stream>>>((const int*)(ws + DEG2_OFF), (int*)(ws + OFF2_OFF),
                                 (int*)(ws + CUR2_OFF), NT2);
  kc_place<<<(N_EDGES + 255) / 256, 256, 0, stream>>>(
      ei, (int*)(ws + CUR1_OFF), (int*)(ws + ES1_OFF),
      (int*)(ws + CUR2_OFF), (int*)(ws + ES2_OFF));

  // conv1 fused (both dtype variants; non-matching early-returns)
  run_stages<float>(d_in, ws, stream, 1);
  run_stages<bf16>(d_in, ws, stream, 1);

  // cart/maxv (dtype-free, needs pos2)
  k3_cart<<<(N_EDGES + 255) / 256, 256, 0, stream>>>(
      ei, ws + P2_OFF, ws + CT_OFF, (unsigned int*)(ws + MV_OFF));

  // conv2 fused (both dtype variants)
  run_stages<float>(d_in, ws, stream, 2);
  run_stages<bf16>(d_in, ws, stream, 2);

  // pool2 + head
  k6_pool2<<<(N3 / K6CH + 4) / 4, 256, 0, stream>>>(
      ws + H2_OFF, batch, ws + GS_OFF, ws + GC_OFF);
  k7_head<float><<<NGRAPH, 128, 0, stream>>>(
      flag, ws + GS_OFF, ws + GC_OFF,
      (const float*)d_in[15], (const float*)d_in[16],
      (const float*)d_in[17], (const float*)d_in[18], (float*)d_out);
  k7_head<bf16><<<NGRAPH, 128, 0, stream>>>(
      flag, ws + GS_OFF, ws + GC_OFF,
      (const bf16*)d_in[15], (const bf16*)d_in[16],
      (const bf16*)d_in[17], (const bf16*)d_in[18], (bf16*)d_out);
}

// Round 3
// 434.109 us; speedup vs baseline: 2.1623x; 2.1623x over previous
//
#include <hip/hip_runtime.h>
#include <hip/hip_bf16.h>

#define N_NODES 30000
#define N_EDGES 120000
#define NGRAPH  512
#define N2      15000
#define N3      7500
#define NC      10

#define TSN   4                 // src pooled-nodes per tile in k4_src
#define NTS   (N2 / TSN)        // 3750

// scan chunking: arrays scanned are deg1(30001), deg2(15001), degS(3751)
#define SC_C1 118
#define SC_C2 59
#define SC_CS 15
#define SC_CT (SC_C1 + SC_C2 + SC_CS)   // 192

typedef __hip_bfloat16 bf16;

__device__ __forceinline__ float lo(const float* p, int i) { return p[i]; }
__device__ __forceinline__ float lo(const bf16* p, int i) { return __bfloat162float(p[i]); }
__device__ __forceinline__ void sto(float* p, int i, float v) { p[i] = v; }
__device__ __forceinline__ void sto(bf16* p, int i, float v) { p[i] = __float2bfloat16(v); }
__device__ __forceinline__ float elu(float x) { return x > 0.f ? x : expm1f(x); }
template <typename T> __host__ __device__ constexpr int want_flag() { return sizeof(T) == 4 ? 1 : 0; }

// ---------------- workspace layout (4-byte units) ----------------
// zero region (memset each call):
#define MV_OFF    0         // maxv (uint bits): 1
#define GS_OFF    1         // gsum: 512*64 = 32768
#define GC_OFF    32769     // gcnt: 512
#define DEG1_OFF  33281     // in-degree per node (int): 30000
#define DEG2_OFF  63281     // valid in-degree per pooled node (int): 15000
#define DEGS_OFF  78281     // valid out-degree per src tile (int): 3750
#define ZERO_FLOATS 82031
// non-zero region:
#define OFF1_OFF  82031     // conv1 CSR offsets (int): 30001
#define CUR1_OFF  112032    // 30000
#define OFF2_OFF  142032    // conv2 dest CSR offsets (int): 15001
#define CUR2_OFF  157033    // 15000
#define OFFS_OFF  172033    // conv2 src-tile CSR offsets (int): 3751
#define CURS_OFF  175784    // 3750
#define BSUM_OFF  179534    // scan chunk sums (int): 192
#define ES1_OFF   179726    // conv1 dest-sorted edge ids (int): 120000
#define ESS_OFF   299726    // conv2 src-tile-sorted edge ids (int): 120000
#define DPOS_OFF  419726    // edge -> dest-sorted row (int): 120000
#define X2_OFF    539726    // x2: N2*32 = 480000
#define P2_OFF    1019726   // pos2: N2*2 = 30000
#define CT_OFF    1049726   // cart: E*2 = 240000
#define H2_OFF    1289726   // h2: N2*64 = 960000
#define MSG_OFF   2249726   // message buffer: E*64 = 7680000
#define FLAG_OFF  9929726   // dtype flag (int)
// total = 9929727 floats ~= 39.7 MB

// ---------------- dtype detector
__global__ __launch_bounds__(256) void k0_detect(const void* x, const void* ea, int* flag) {
  const bf16* xb = (const bf16*)x;
  const bf16* eb = (const bf16*)ea;
  int tid = threadIdx.x;
  float a = __bfloat162float(xb[tid]);
  float b = __bfloat162float(eb[tid]);
  int bad = (!(fabsf(a) < 1e3f)) || (!(fabsf(b) < 1e3f));
  unsigned long long m = __ballot(bad);
  __shared__ int anyb[4];
  int w = tid >> 6;
  if ((tid & 63) == 0) anyb[w] = (m != 0ULL) ? 1 : 0;
  __syncthreads();
  if (tid == 0) flag[0] = (anyb[0] | anyb[1] | anyb[2] | anyb[3]);
}

// ---------------- degree histograms (dtype-free)
__global__ __launch_bounds__(256) void kc_deg(const int* __restrict__ ei,
                                              int* __restrict__ deg1,
                                              int* __restrict__ deg2,
                                              int* __restrict__ degS) {
  int e = blockIdx.x * 256 + threadIdx.x;
  if (e >= N_EDGES) return;
  int row = ei[e], col = ei[N_EDGES + e];
  atomicAdd(deg1 + col, 1);
  int r2 = row >> 1, c2 = col >> 1;
  if (r2 != c2) {
    atomicAdd(deg2 + c2, 1);
    atomicAdd(degS + (r2 >> 2), 1);
  }
}

// ---------------- hierarchical exclusive scan over the three deg arrays
__global__ __launch_bounds__(256) void ks_scanA(
    const int* __restrict__ deg1, const int* __restrict__ deg2, const int* __restrict__ degS,
    int* __restrict__ off1, int* __restrict__ off2, int* __restrict__ offS,
    int* __restrict__ bsum) {
  __shared__ int buf[256];
  int c = blockIdx.x, tid = threadIdx.x;
  const int* deg; int* off; int n, local;
  if (c < SC_C1)              { deg = deg1; off = off1; n = 30000; local = c; }
  else if (c < SC_C1 + SC_C2) { deg = deg2; off = off2; n = 15000; local = c - SC_C1; }
  else                        { deg = degS; off = offS; n = 3750;  local = c - SC_C1 - SC_C2; }
  int i = local * 256 + tid;
  int v = (i < n) ? deg[i] : 0;
  buf[tid] = v;
  __syncthreads();
  for (int s = 1; s < 256; s <<= 1) {
    int t = (tid >= s) ? buf[tid - s] : 0;
    __syncthreads();
    buf[tid] += t;
    __syncthreads();
  }
  if (i <= n) off[i] = buf[tid] - v;
  if (tid == 255) bsum[c] = buf[255];
}

__global__ __launch_bounds__(256) void ks_scanB(int* __restrict__ bsum) {
  __shared__ int buf[256];
  int a = blockIdx.x, tid = threadIdx.x;
  int nc, cb;
  if (a == 0)      { nc = SC_C1; cb = 0; }
  else if (a == 1) { nc = SC_C2; cb = SC_C1; }
  else             { nc = SC_CS; cb = SC_C1 + SC_C2; }
  int v = (tid < nc) ? bsum[cb + tid] : 0;
  buf[tid] = v;
  __syncthreads();
  for (int s = 1; s < 256; s <<= 1) {
    int t = (tid >= s) ? buf[tid - s] : 0;
    __syncthreads();
    buf[tid] += t;
    __syncthreads();
  }
  if (tid < nc) bsum[cb + tid] = buf[tid] - v;
}

__global__ __launch_bounds__(256) void ks_scanC(
    int* __restrict__ off1, int* __restrict__ off2, int* __restrict__ offS,
    int* __restrict__ cur1, int* __restrict__ cur2, int* __restrict__ curS,
    const int* __restrict__ bsum) {
  int c = blockIdx.x, tid = threadIdx.x;
  int* off; int* cur; int n, local;
  if (c < SC_C1)              { off = off1; cur = cur1; n = 30000; local = c; }
  else if (c < SC_C1 + SC_C2) { off = off2; cur = cur2; n = 15000; local = c - SC_C1; }
  else                        { off = offS; cur = curS; n = 3750;  local = c - SC_C1 - SC_C2; }
  int add = bsum[c];
  int i = local * 256 + tid;
  if (i <= n) off[i] += add;
  if (i < n) cur[i] = off[i];
}

// ---------------- edge placement into CSR lists (dtype-free)
__global__ __launch_bounds__(256) void kc_place(const int* __restrict__ ei,
                                                int* __restrict__ cur1, int* __restrict__ es1,
                                                int* __restrict__ cur2, int* __restrict__ dpos,
                                                int* __restrict__ curS, int* __restrict__ ess) {
  int e = blockIdx.x * 256 + threadIdx.x;
  if (e >= N_EDGES) return;
  int row = ei[e], col = ei[N_EDGES + e];
  int p = atomicAdd(cur1 + col, 1);
  es1[p] = e;
  int r2 = row >> 1, c2 = col >> 1;
  if (r2 != c2) {
    int q = atomicAdd(cur2 + c2, 1);
    dpos[e] = q;                       // global dest-sorted row for this edge's message
    int u = atomicAdd(curS + (r2 >> 2), 1);
    ess[u] = e;
  }
}

// ---------------- conv1 fused: per-dest register aggregation + node update + pair pool
// 32-lane group per pooled node m; walks edge lists of nodes 2m, 2m+1. No atomics.
template <typename T>
__global__ __launch_bounds__(256) void k1_node(
    const int* __restrict__ flag,
    const T* __restrict__ x, const T* __restrict__ ea, const T* __restrict__ pos,
    const int* __restrict__ ei,
    const T* __restrict__ w1a, const T* __restrict__ b1a,
    const T* __restrict__ w1b, const T* __restrict__ b1b,
    const T* __restrict__ root1, const T* __restrict__ bias1,
    const int* __restrict__ off1, const int* __restrict__ es1,
    float* __restrict__ x2, float* __restrict__ pos2) {
  if (flag[0] != want_flag<T>()) return;
  __shared__ float w1a_l[50];
  __shared__ float b1a_l[25];
  __shared__ float w1b_l[800];   // [k*32+o]
  __shared__ float b1b_l[32];
  __shared__ float r1_l[32];
  __shared__ float bs1_l[32];
  int tid = threadIdx.x;
  for (int j = tid; j < 50; j += 256) w1a_l[j] = lo(w1a, j);
  for (int j = tid; j < 25; j += 256) b1a_l[j] = lo(b1a, j);
  for (int j = tid; j < 800; j += 256) w1b_l[j] = lo(w1b, j);
  if (tid < 32) {
    b1b_l[tid] = lo(b1b, tid);
    r1_l[tid] = lo(root1, tid);
    bs1_l[tid] = lo(bias1, tid);
  }
  __syncthreads();
  int m = blockIdx.x * 8 + (tid >> 5);   // pooled node id, exactly N2 groups
  int o = tid & 31;
  float h[2];
#pragma unroll
  for (int pi = 0; pi < 2; ++pi) {
    int n = 2 * m + pi;
    int j0 = off1[n], j1 = off1[n + 1];
    float acc = 0.f;
    for (int j = j0; j < j1; ++j) {
      int e = es1[j];
      int src = ei[e];
      float a0 = lo(ea, 2 * e), a1 = lo(ea, 2 * e + 1);
      float xv = lo(x, src);
      float s = b1b_l[o];
#pragma unroll
      for (int k = 0; k < 25; ++k) {
        float tk = fmaxf(a0 * w1a_l[k] + a1 * w1a_l[25 + k] + b1a_l[k], 0.f);
        s += tk * w1b_l[k * 32 + o];
      }
      acc += xv * s;
    }
    float c = fmaxf((float)(j1 - j0), 1.f);
    h[pi] = elu(acc / c + lo(x, n) * r1_l[o] + bs1_l[o]);
  }
  x2[m * 32 + o] = fmaxf(h[0], h[1]);
  if (o < 2)
    pos2[m * 2 + o] = 0.5f * (lo(pos, (2 * m) * 2 + o) + lo(pos, (2 * m + 1) * 2 + o));
}

// ---------------- cart + global abs-max (fp32 intermediates only)
__global__ __launch_bounds__(256) void k3_cart(
    const int* __restrict__ ei, const float* __restrict__ pos2,
    float* __restrict__ cart, unsigned int* __restrict__ maxv) {
  int e = blockIdx.x * 256 + threadIdx.x;
  float m = 0.f;
  if (e < N_EDGES) {
    int r2 = ei[e] >> 1, c2 = ei[N_EDGES + e] >> 1;
    float cx = 0.f, cy = 0.f;
    if (r2 != c2) {
      cx = pos2[2 * c2] - pos2[2 * r2];
      cy = pos2[2 * c2 + 1] - pos2[2 * r2 + 1];
    }
    cart[2 * e] = cx;
    cart[2 * e + 1] = cy;
    m = fmaxf(fabsf(cx), fabsf(cy));
  }
#pragma unroll
  for (int s = 32; s > 0; s >>= 1)
    m = fmaxf(m, __shfl_xor(m, s, 64));
  __shared__ float wm[4];
  int lane = threadIdx.x & 63, wid = threadIdx.x >> 6;
  if (lane == 0) wm[wid] = m;
  __syncthreads();
  if (threadIdx.x == 0) {
    float mm = fmaxf(fmaxf(wm[0], wm[1]), fmaxf(wm[2], wm[3]));
    atomicMax(maxv, __float_as_uint(mm));
  }
}

// ---------------- conv2 pass A: source-tile Y factorization, coalesced message stores.
// Y[s][k][o] = sum_i x2[s,i]*w2b[k,i*64+o]  (row 25 from b2b); per edge:
// msg[dpos(e)][o] = Y[s][25][o] + sum_k relu(ea2@w2a+b2a)[k] * Y[s][k][o]
template <typename T>
__global__ __launch_bounds__(256) void k4_src(
    const int* __restrict__ flag,
    const int* __restrict__ ei, const float* __restrict__ cart, const float* __restrict__ maxv_f,
    const float* __restrict__ x2,
    const T* __restrict__ w2a, const T* __restrict__ b2a,
    const T* __restrict__ w2b, const T* __restrict__ b2b,
    const int* __restrict__ offS, const int* __restrict__ ess,
    const int* __restrict__ dpos,
    float* __restrict__ msg) {
  if (flag[0] != want_flag<T>()) return;
  __shared__ float Y[TSN][26][64];   // 26624 B
  __shared__ float xl[TSN][32];
  __shared__ float w2a_l[50];
  __shared__ float b2a_l[25];
  int tid = threadIdx.x, t = blockIdx.x;
  int n0 = t * TSN;
  if (tid < TSN * 32) xl[tid >> 5][tid & 31] = x2[n0 * 32 + tid];
  for (int j = tid; j < 50; j += 256) w2a_l[j] = lo(w2a, j);
  for (int j = tid; j < 25; j += 256) b2a_l[j] = lo(b2a, j);
  __syncthreads();
  int w = tid >> 6, o = tid & 63;
  for (int kk = w; kk < 26; kk += 4) {
    const T* srcp = (kk < 25) ? (w2b + kk * 2048) : b2b;
    float a0 = 0.f, a1 = 0.f, a2 = 0.f, a3 = 0.f;
#pragma unroll 8
    for (int i = 0; i < 32; ++i) {
      float q = lo(srcp, i * 64 + o);
      a0 += xl[0][i] * q;
      a1 += xl[1][i] * q;
      a2 += xl[2][i] * q;
      a3 += xl[3][i] * q;
    }
    Y[0][kk][o] = a0; Y[1][kk][o] = a1; Y[2][kk][o] = a2; Y[3][kk][o] = a3;
  }
  __syncthreads();
  float inv = 0.5f / maxv_f[0];
  int j0 = offS[t], j1 = offS[t + 1];
  for (int j = j0 + w; j < j1; j += 4) {
    int e = ess[j];
    int r2 = ei[e] >> 1;
    int nl = r2 & (TSN - 1);
    int dp = dpos[e];
    float ax = cart[2 * e] * inv + 0.5f;
    float ay = cart[2 * e + 1] * inv + 0.5f;
    float acc = Y[nl][25][o];
#pragma unroll
    for (int k = 0; k < 25; ++k) {
      float tk = fmaxf(ax * w2a_l[k] + ay * w2a_l[25 + k] + b2a_l[k], 0.f);
      acc += tk * Y[nl][k][o];
    }
    msg[(size_t)dp * 64 + o] = acc;   // coalesced 256B store, no atomics
  }
}

// ---------------- conv2 pass B: per-dest contiguous gather + mean + root2 + bias2 + elu
template <typename T>
__global__ __launch_bounds__(256) void k5_gather(
    const int* __restrict__ flag,
    const float* __restrict__ msg, const int* __restrict__ off2,
    const float* __restrict__ x2,
    const T* __restrict__ root2, const T* __restrict__ bias2,
    float* __restrict__ h2) {
  if (flag[0] != want_flag<T>()) return;
  __shared__ float r2_l[2048];   // [i*64+o]
  __shared__ float b2_l[64];
  int tid = threadIdx.x;
  for (int j = tid; j < 2048; j += 256) r2_l[j] = lo(root2, j);
  if (tid < 64) b2_l[tid] = lo(bias2, tid);
  __syncthreads();
  int d = blockIdx.x * 4 + (tid >> 6);
  int o = tid & 63;
  int j0 = off2[d], j1 = off2[d + 1];
  float s = 0.f;
  for (int j = j0; j < j1; ++j) s += msg[(size_t)j * 64 + o];
  float c = fmaxf((float)(j1 - j0), 1.f);
  float r = b2_l[o];
  const float* xr = x2 + d * 32;
#pragma unroll 8
  for (int i = 0; i < 32; ++i) r += xr[i] * r2_l[i * 64 + o];
  h2[d * 64 + o] = elu(s / c + r);
}

// ---------------- pair max-pool 2 + per-graph segmented sum
#define K6CH 16
__global__ __launch_bounds__(256) void k6_pool2(
    const float* __restrict__ h2, const int* __restrict__ batch,
    float* __restrict__ gsum, float* __restrict__ gcnt) {
  int wid = blockIdx.x * 4 + (threadIdx.x >> 6);
  int lane = threadIdx.x & 63;
  int m0 = wid * K6CH;
  if (m0 >= N3) return;
  int m1 = m0 + K6CH < N3 ? m0 + K6CH : N3;
  int bcur = batch[4 * m0];
  float acc = 0.f, cnt = 0.f;
  for (int m = m0; m < m1; ++m) {
    int b = batch[4 * m];
    float v = fmaxf(h2[(2 * m) * 64 + lane], h2[(2 * m + 1) * 64 + lane]);
    if (b != bcur) {
      atomicAdd(gsum + bcur * 64 + lane, acc);
      if (lane == 0) atomicAdd(gcnt + bcur, cnt);
      acc = 0.f; cnt = 0.f; bcur = b;
    }
    acc += v; cnt += 1.f;
  }
  atomicAdd(gsum + bcur * 64 + lane, acc);
  if (lane == 0) atomicAdd(gcnt + bcur, cnt);
}

// ---------------- graph mean -> fc1 -> elu -> fc2 -> log_softmax
template <typename T>
__global__ __launch_bounds__(128) void k7_head(
    const int* __restrict__ flag,
    const float* __restrict__ gsum, const float* __restrict__ gcnt,
    const T* __restrict__ fc1_w, const T* __restrict__ fc1_b,
    const T* __restrict__ fc2_w, const T* __restrict__ fc2_b,
    T* __restrict__ out) {
  if (flag[0] != want_flag<T>()) return;
  __shared__ float gv[64];
  __shared__ float h1s[128];
  __shared__ float zs[NC];
  __shared__ float lse;
  int g = blockIdx.x, tid = threadIdx.x;
  if (tid < 64) gv[tid] = gsum[g * 64 + tid] / fmaxf(gcnt[g], 1.f);
  __syncthreads();
  float a = lo(fc1_b, tid);
#pragma unroll 8
  for (int o = 0; o < 64; ++o) a += gv[o] * lo(fc1_w, o * 128 + tid);
  h1s[tid] = elu(a);
  __syncthreads();
  if (tid < NC) {
    float s = lo(fc2_b, tid);
    for (int j = 0; j < 128; ++j) s += h1s[j] * lo(fc2_w, j * NC + tid);
    zs[tid] = s;
  }
  __syncthreads();
  if (tid == 0) {
    float m = -1e30f;
    for (int c = 0; c < NC; ++c) m = fmaxf(m, zs[c]);
    float s = 0.f;
    for (int c = 0; c < NC; ++c) s += expf(zs[c] - m);
    lse = m + logf(s);
  }
  __syncthreads();
  if (tid < NC) sto(out, g * NC + tid, zs[tid] - lse);
}

template <typename T>
static void run_conv1(void* const* d_in, float* ws, hipStream_t stream) {
  const int* ei   = (const int*)d_in[19];
  const int* flag = (const int*)(ws + FLAG_OFF);
  k1_node<T><<<N2 / 8, 256, 0, stream>>>(
      flag, (const T*)d_in[0], (const T*)d_in[1], (const T*)d_in[2], ei,
      (const T*)d_in[3], (const T*)d_in[4], (const T*)d_in[5], (const T*)d_in[6],
      (const T*)d_in[7], (const T*)d_in[8],
      (const int*)(ws + OFF1_OFF), (const int*)(ws + ES1_OFF),
      ws + X2_OFF, ws + P2_OFF);
}

template <typename T>
static void run_conv2(void* const* d_in, float* ws, hipStream_t stream) {
  const int* ei   = (const int*)d_in[19];
  const int* flag = (const int*)(ws + FLAG_OFF);
  k4_src<T><<<NTS, 256, 0, stream>>>(
      flag, ei, ws + CT_OFF, ws + MV_OFF, ws + X2_OFF,
      (const T*)d_in[9], (const T*)d_in[10], (const T*)d_in[11], (const T*)d_in[12],
      (const int*)(ws + OFFS_OFF), (const int*)(ws + ESS_OFF),
      (const int*)(ws + DPOS_OFF), ws + MSG_OFF);
  k5_gather<T><<<N2 / 4, 256, 0, stream>>>(
      flag, ws + MSG_OFF, (const int*)(ws + OFF2_OFF), ws + X2_OFF,
      (const T*)d_in[13], (const T*)d_in[14], ws + H2_OFF);
}

extern "C" void kernel_launch(void* const* d_in, const int* in_sizes, int n_in,
                              void* d_out, int out_size, void* d_ws, size_t ws_size,
                              hipStream_t stream) {
  float* ws = (float*)d_ws;
  const int* flag = (const int*)(ws + FLAG_OFF);
  const int* ei = (const int*)d_in[19];
  const int* batch = (const int*)d_in[20];

  k0_detect<<<1, 256, 0, stream>>>(d_in[0], d_in[1], (int*)(ws + FLAG_OFF));
  hipMemsetAsync(d_ws, 0, (size_t)ZERO_FLOATS * 4, stream);

  // per-node CSR builds (dtype-free): histogram -> hierarchical scan -> placement
  kc_deg<<<(N_EDGES + 255) / 256, 256, 0, stream>>>(
      ei, (int*)(ws + DEG1_OFF), (int*)(ws + DEG2_OFF), (int*)(ws + DEGS_OFF));
  ks_scanA<<<SC_CT, 256, 0, stream>>>(
      (const int*)(ws + DEG1_OFF), (const int*)(ws + DEG2_OFF), (const int*)(ws + DEGS_OFF),
      (int*)(ws + OFF1_OFF), (int*)(ws + OFF2_OFF), (int*)(ws + OFFS_OFF),
      (int*)(ws + BSUM_OFF));
  ks_scanB<<<3, 256, 0, stream>>>((int*)(ws + BSUM_OFF));
  ks_scanC<<<SC_CT, 256, 0, stream>>>(
      (int*)(ws + OFF1_OFF), (int*)(ws + OFF2_OFF), (int*)(ws + OFFS_OFF),
      (int*)(ws + CUR1_OFF), (int*)(ws + CUR2_OFF), (int*)(ws + CURS_OFF),
      (const int*)(ws + BSUM_OFF));
  kc_place<<<(N_EDGES + 255) / 256, 256, 0, stream>>>(
      ei, (int*)(ws + CUR1_OFF), (int*)(ws + ES1_OFF),
      (int*)(ws + CUR2_OFF), (int*)(ws + DPOS_OFF),
      (int*)(ws + CURS_OFF), (int*)(ws + ESS_OFF));

  // conv1 + pool1 (both dtype variants; non-matching early-returns)
  run_conv1<float>(d_in, ws, stream);
  run_conv1<bf16>(d_in, ws, stream);

  // cart/maxv (dtype-free, needs pos2)
  k3_cart<<<(N_EDGES + 255) / 256, 256, 0, stream>>>(
      ei, ws + P2_OFF, ws + CT_OFF, (unsigned int*)(ws + MV_OFF));

  // conv2: factorized messages (pass A) + contiguous gather (pass B)
  run_conv2<float>(d_in, ws, stream);
  run_conv2<bf16>(d_in, ws, stream);

  // pool2 + head
  k6_pool2<<<(N3 / K6CH + 4) / 4, 256, 0, stream>>>(
      ws + H2_OFF, batch, ws + GS_OFF, ws + GC_OFF);
  k7_head<float><<<NGRAPH, 128, 0, stream>>>(
      flag, ws + GS_OFF, ws + GC_OFF,
      (const float*)d_in[15], (const float*)d_in[16],
      (const float*)d_in[17], (const float*)d_in[18], (float*)d_out);
  k7_head<bf16><<<NGRAPH, 128, 0, stream>>>(
      flag, ws + GS_OFF, ws + GC_OFF,
      (const bf16*)d_in[15], (const bf16*)d_in[16],
      (const bf16*)d_in[17], (const bf16*)d_in[18], (bf16*)d_out);
}

// Round 4
// 283.643 us; speedup vs baseline: 3.3093x; 1.5305x over previous
//
#include <hip/hip_runtime.h>
#include <hip/hip_bf16.h>

#define N_NODES 30000
#define N_EDGES 120000
#define NGRAPH  512
#define N2      15000
#define N3      7500
#define NC      10

#define TSN   4                 // src pooled-nodes per tile in k4_src
#define NTS   (N2 / TSN)        // 3750
#define EC4   64                // edge chunk, k4
#define NB1   32                // original nodes per block, k1
#define NBLK1 ((N_NODES + NB1 - 1) / NB1)   // 938
#define EC1   128               // edge chunk, k1

// scan chunking: arrays scanned are deg1(30001), deg2(15001), degS(3751)
#define SC_C1 118
#define SC_C2 59
#define SC_CS 15
#define SC_CT (SC_C1 + SC_C2 + SC_CS)   // 192

typedef __hip_bfloat16 bf16;

__device__ __forceinline__ float lo(const float* p, int i) { return p[i]; }
__device__ __forceinline__ float lo(const bf16* p, int i) { return __bfloat162float(p[i]); }
__device__ __forceinline__ void sto(float* p, int i, float v) { p[i] = v; }
__device__ __forceinline__ void sto(bf16* p, int i, float v) { p[i] = __float2bfloat16(v); }
__device__ __forceinline__ float elu(float x) { return x > 0.f ? x : expm1f(x); }
template <typename T> __host__ __device__ constexpr int want_flag() { return sizeof(T) == 4 ? 1 : 0; }

// ---------------- workspace layout (4-byte units) ----------------
// zero region (memset each call):
#define MV_OFF    0         // maxv (uint bits): 1
#define GS_OFF    1         // gsum: 512*64 = 32768
#define GC_OFF    32769     // gcnt: 512
#define DEG1_OFF  33281     // in-degree per node (int): 30000
#define DEG2_OFF  63281     // valid in-degree per pooled node (int): 15000
#define DEGS_OFF  78281     // valid out-degree per src tile (int): 3750
#define ZERO_FLOATS 82031
// non-zero region:
#define OFF1_OFF  82031     // conv1 CSR offsets (int): 30001
#define CUR1_OFF  112032    // 30000
#define OFF2_OFF  142032    // conv2 dest CSR offsets (int): 15001
#define CUR2_OFF  157033    // 15000
#define OFFS_OFF  172033    // conv2 src-tile CSR offsets (int): 3751
#define CURS_OFF  175784    // 3750
#define BSUM_OFF  179534    // scan chunk sums (int): 192
#define ES1_OFF   179726    // conv1 dest-sorted edge ids (int): 120000
#define ESS_OFF   299726    // conv2 src-tile-sorted edge ids (int): 120000
#define DPOS_OFF  419726    // edge -> dest-sorted row (int): 120000
#define X2_OFF    539726    // x2: N2*32 = 480000
#define P2_OFF    1019726   // pos2: N2*2 = 30000
#define CT_OFF    1049726   // cart: E*2 = 240000
#define H2_OFF    1289726   // h2: N2*64 = 960000
#define MSG_OFF   2249726   // message buffer: E*64 = 7680000
#define FLAG_OFF  9929726   // dtype flag (int)
// total = 9929727 floats ~= 39.7 MB

// ---------------- dtype detector
__global__ __launch_bounds__(256) void k0_detect(const void* x, const void* ea, int* flag) {
  const bf16* xb = (const bf16*)x;
  const bf16* eb = (const bf16*)ea;
  int tid = threadIdx.x;
  float a = __bfloat162float(xb[tid]);
  float b = __bfloat162float(eb[tid]);
  int bad = (!(fabsf(a) < 1e3f)) || (!(fabsf(b) < 1e3f));
  unsigned long long m = __ballot(bad);
  __shared__ int anyb[4];
  int w = tid >> 6;
  if ((tid & 63) == 0) anyb[w] = (m != 0ULL) ? 1 : 0;
  __syncthreads();
  if (tid == 0) flag[0] = (anyb[0] | anyb[1] | anyb[2] | anyb[3]);
}

// ---------------- degree histograms (dtype-free)
__global__ __launch_bounds__(256) void kc_deg(const int* __restrict__ ei,
                                              int* __restrict__ deg1,
                                              int* __restrict__ deg2,
                                              int* __restrict__ degS) {
  int e = blockIdx.x * 256 + threadIdx.x;
  if (e >= N_EDGES) return;
  int row = ei[e], col = ei[N_EDGES + e];
  atomicAdd(deg1 + col, 1);
  int r2 = row >> 1, c2 = col >> 1;
  if (r2 != c2) {
    atomicAdd(deg2 + c2, 1);
    atomicAdd(degS + (r2 >> 2), 1);
  }
}

// ---------------- hierarchical exclusive scan over the three deg arrays
__global__ __launch_bounds__(256) void ks_scanA(
    const int* __restrict__ deg1, const int* __restrict__ deg2, const int* __restrict__ degS,
    int* __restrict__ off1, int* __restrict__ off2, int* __restrict__ offS,
    int* __restrict__ bsum) {
  __shared__ int buf[256];
  int c = blockIdx.x, tid = threadIdx.x;
  const int* deg; int* off; int n, local;
  if (c < SC_C1)              { deg = deg1; off = off1; n = 30000; local = c; }
  else if (c < SC_C1 + SC_C2) { deg = deg2; off = off2; n = 15000; local = c - SC_C1; }
  else                        { deg = degS; off = offS; n = 3750;  local = c - SC_C1 - SC_C2; }
  int i = local * 256 + tid;
  int v = (i < n) ? deg[i] : 0;
  buf[tid] = v;
  __syncthreads();
  for (int s = 1; s < 256; s <<= 1) {
    int t = (tid >= s) ? buf[tid - s] : 0;
    __syncthreads();
    buf[tid] += t;
    __syncthreads();
  }
  if (i <= n) off[i] = buf[tid] - v;
  if (tid == 255) bsum[c] = buf[255];
}

__global__ __launch_bounds__(256) void ks_scanB(int* __restrict__ bsum) {
  __shared__ int buf[256];
  int a = blockIdx.x, tid = threadIdx.x;
  int nc, cb;
  if (a == 0)      { nc = SC_C1; cb = 0; }
  else if (a == 1) { nc = SC_C2; cb = SC_C1; }
  else             { nc = SC_CS; cb = SC_C1 + SC_C2; }
  int v = (tid < nc) ? bsum[cb + tid] : 0;
  buf[tid] = v;
  __syncthreads();
  for (int s = 1; s < 256; s <<= 1) {
    int t = (tid >= s) ? buf[tid - s] : 0;
    __syncthreads();
    buf[tid] += t;
    __syncthreads();
  }
  if (tid < nc) bsum[cb + tid] = buf[tid] - v;
}

__global__ __launch_bounds__(256) void ks_scanC(
    int* __restrict__ off1, int* __restrict__ off2, int* __restrict__ offS,
    int* __restrict__ cur1, int* __restrict__ cur2, int* __restrict__ curS,
    const int* __restrict__ bsum) {
  int c = blockIdx.x, tid = threadIdx.x;
  int* off; int* cur; int n, local;
  if (c < SC_C1)              { off = off1; cur = cur1; n = 30000; local = c; }
  else if (c < SC_C1 + SC_C2) { off = off2; cur = cur2; n = 15000; local = c - SC_C1; }
  else                        { off = offS; cur = curS; n = 3750;  local = c - SC_C1 - SC_C2; }
  int add = bsum[c];
  int i = local * 256 + tid;
  if (i <= n) off[i] += add;
  if (i < n) cur[i] = off[i];
}

// ---------------- edge placement into CSR lists (dtype-free)
__global__ __launch_bounds__(256) void kc_place(const int* __restrict__ ei,
                                                int* __restrict__ cur1, int* __restrict__ es1,
                                                int* __restrict__ cur2, int* __restrict__ dpos,
                                                int* __restrict__ curS, int* __restrict__ ess) {
  int e = blockIdx.x * 256 + threadIdx.x;
  if (e >= N_EDGES) return;
  int row = ei[e], col = ei[N_EDGES + e];
  int p = atomicAdd(cur1 + col, 1);
  es1[p] = e;
  int r2 = row >> 1, c2 = col >> 1;
  if (r2 != c2) {
    int q = atomicAdd(cur2 + c2, 1);
    dpos[e] = q;
    int u = atomicAdd(curS + (r2 >> 2), 1);
    ess[u] = e;
  }
}

// ---------------- conv1 fused v2: cooperative edge staging, wave-per-node accumulate
// Block handles 32 original nodes (16 pooled); their dest-sorted edges are contiguous.
template <typename T>
__global__ __launch_bounds__(256, 4) void k1_blk(
    const int* __restrict__ flag,
    const T* __restrict__ x, const T* __restrict__ ea, const T* __restrict__ pos,
    const int* __restrict__ ei,
    const T* __restrict__ w1a, const T* __restrict__ b1a,
    const T* __restrict__ w1b, const T* __restrict__ b1b,
    const T* __restrict__ root1, const T* __restrict__ bias1,
    const int* __restrict__ off1, const int* __restrict__ es1,
    float* __restrict__ x2, float* __restrict__ pos2) {
  if (flag[0] != want_flag<T>()) return;
  __shared__ float w1a_l[50];
  __shared__ float b1a_l[25];
  __shared__ float w1b_l[800];       // [k*32+o]
  __shared__ float b1b_l[32];
  __shared__ float r1_l[32];
  __shared__ float bs1_l[32];
  __shared__ float tl2[25][EC1];     // [k][edge]: write conflict-free, read broadcast
  __shared__ float xsl[EC1];
  __shared__ float hbuf[NB1][33];
  __shared__ int offl[NB1 + 1];
  int tid = threadIdx.x, t = blockIdx.x;
  int n0 = t * NB1;
  for (int j = tid; j < 50; j += 256) w1a_l[j] = lo(w1a, j);
  for (int j = tid; j < 25; j += 256) b1a_l[j] = lo(b1a, j);
  for (int j = tid; j < 800; j += 256) w1b_l[j] = lo(w1b, j);
  if (tid < 32) {
    b1b_l[tid] = lo(b1b, tid);
    r1_l[tid] = lo(root1, tid);
    bs1_l[tid] = lo(bias1, tid);
  }
  if (tid <= NB1) {
    int n = n0 + tid; if (n > N_NODES) n = N_NODES;
    offl[tid] = off1[n];
  }
  __syncthreads();
  int jbeg = offl[0], jend = offl[NB1];
  int wv = tid >> 6, lane = tid & 63, o = lane & 31, hf = lane >> 5;
  float acc[8];
#pragma unroll
  for (int s = 0; s < 8; ++s) acc[s] = 0.f;
  for (int jb = jbeg; jb < jend; jb += EC1) {
    int ecnt = jend - jb; if (ecnt > EC1) ecnt = EC1;
    __syncthreads();   // protect staging buffers from previous chunk's readers
    if (tid < ecnt) {
      int e = es1[jb + tid];
      float a0 = lo(ea, 2 * e), a1 = lo(ea, 2 * e + 1);
      xsl[tid] = lo(x, ei[e]);
#pragma unroll
      for (int k = 0; k < 25; ++k)
        tl2[k][tid] = fmaxf(a0 * w1a_l[k] + a1 * w1a_l[25 + k] + b1a_l[k], 0.f);
    }
    __syncthreads();
    // wave wv owns nodes nl = wv + 4*s; halves split the edge list, no divergence
#pragma unroll
    for (int s = 0; s < 8; ++s) {
      int nl = wv + 4 * s;
      int lj = offl[nl]; if (lj < jb) lj = jb;
      int hj = offl[nl + 1]; if (hj > jb + ecnt) hj = jb + ecnt;
      for (int j = lj + hf; j < hj; j += 2) {
        int sj = j - jb;
        float macc = b1b_l[o];
#pragma unroll
        for (int k = 0; k < 25; ++k) macc += tl2[k][sj] * w1b_l[k * 32 + o];
        acc[s] += xsl[sj] * macc;
      }
    }
  }
  // cross-half reduce + node update + elu -> hbuf
#pragma unroll
  for (int s = 0; s < 8; ++s) {
    int nl = wv + 4 * s;
    float a = acc[s] + __shfl_xor(acc[s], 32, 64);
    int n = n0 + nl;
    if (hf == 0 && n < N_NODES) {
      float c = (float)(offl[nl + 1] - offl[nl]);
      c = fmaxf(c, 1.f);
      hbuf[nl][o] = elu(a / c + lo(x, n) * r1_l[o] + bs1_l[o]);
    }
  }
  __syncthreads();
  // pair max-pool -> x2
  for (int idx = tid; idx < (NB1 / 2) * 32; idx += 256) {
    int pl = idx >> 5, oo = idx & 31;
    int m = t * (NB1 / 2) + pl;
    if (m < N2)
      x2[m * 32 + oo] = fmaxf(hbuf[2 * pl][oo], hbuf[2 * pl + 1][oo]);
  }
  // pos mean-pool -> pos2
  if (tid < NB1) {
    int pl = tid >> 1, c = tid & 1;
    int m = t * (NB1 / 2) + pl;
    if (m < N2)
      pos2[m * 2 + c] = 0.5f * (lo(pos, (2 * m) * 2 + c) + lo(pos, (2 * m + 1) * 2 + c));
  }
}

// ---------------- cart + global abs-max
__global__ __launch_bounds__(256) void k3_cart(
    const int* __restrict__ ei, const float* __restrict__ pos2,
    float* __restrict__ cart, unsigned int* __restrict__ maxv) {
  int e = blockIdx.x * 256 + threadIdx.x;
  float m = 0.f;
  if (e < N_EDGES) {
    int r2 = ei[e] >> 1, c2 = ei[N_EDGES + e] >> 1;
    float cx = 0.f, cy = 0.f;
    if (r2 != c2) {
      cx = pos2[2 * c2] - pos2[2 * r2];
      cy = pos2[2 * c2 + 1] - pos2[2 * r2 + 1];
    }
    cart[2 * e] = cx;
    cart[2 * e + 1] = cy;
    m = fmaxf(fabsf(cx), fabsf(cy));
  }
#pragma unroll
  for (int s = 32; s > 0; s >>= 1)
    m = fmaxf(m, __shfl_xor(m, s, 64));
  __shared__ float wm[4];
  int lane = threadIdx.x & 63, wid = threadIdx.x >> 6;
  if (lane == 0) wm[wid] = m;
  __syncthreads();
  if (threadIdx.x == 0) {
    float mm = fmaxf(fmaxf(wm[0], wm[1]), fmaxf(wm[2], wm[3]));
    atomicMax(maxv, __float_as_uint(mm));
  }
}

// ---------------- conv2 pass A v2: Y in LDS + chunked cooperative edge staging
// Y[s][k][o] = sum_i x2[s,i]*w2b[k,i*64+o] (row 25 = b2b); per edge:
// msg[dpos(e)][o] = Y[s][25][o] + sum_k tl[e][k] * Y[s][k][o]
template <typename T>
__global__ __launch_bounds__(256, 3) void k4_src(
    const int* __restrict__ flag,
    const int* __restrict__ ei, const float* __restrict__ cart, const float* __restrict__ maxv_f,
    const float* __restrict__ x2,
    const T* __restrict__ w2a, const T* __restrict__ b2a,
    const T* __restrict__ w2b, const T* __restrict__ b2b,
    const int* __restrict__ offS, const int* __restrict__ ess,
    const int* __restrict__ dpos,
    float* __restrict__ msg) {
  if (flag[0] != want_flag<T>()) return;
  __shared__ float Y[TSN][26][64];          // 26.6 KB
  __shared__ float xl[TSN][32];
  __shared__ float w2a_l[50];
  __shared__ float b2a_l[25];
  __shared__ __align__(16) float tl[EC4][28];  // 7 KB; 16B rows -> b128-able
  __shared__ int dpl[EC4];
  __shared__ int nll[EC4];
  __shared__ float axl[EC4], ayl[EC4];
  int tid = threadIdx.x, t = blockIdx.x;
  int n0 = t * TSN;
  if (tid < TSN * 32) xl[tid >> 5][tid & 31] = x2[n0 * 32 + tid];
  for (int j = tid; j < 50; j += 256) w2a_l[j] = lo(w2a, j);
  for (int j = tid; j < 25; j += 256) b2a_l[j] = lo(b2a, j);
  __syncthreads();
  int w = tid >> 6, o = tid & 63;
  // stage A: Y fragments
  for (int kk = w; kk < 26; kk += 4) {
    const T* srcp = (kk < 25) ? (w2b + kk * 2048) : b2b;
    float a0 = 0.f, a1 = 0.f, a2 = 0.f, a3 = 0.f;
#pragma unroll 8
    for (int i = 0; i < 32; ++i) {
      float q = lo(srcp, i * 64 + o);
      a0 += xl[0][i] * q;
      a1 += xl[1][i] * q;
      a2 += xl[2][i] * q;
      a3 += xl[3][i] * q;
    }
    Y[0][kk][o] = a0; Y[1][kk][o] = a1; Y[2][kk][o] = a2; Y[3][kk][o] = a3;
  }
  float inv = 0.5f / maxv_f[0];
  int j0 = offS[t], j1 = offS[t + 1];
  for (int jb = j0; jb < j1; jb += EC4) {
    int ecnt = j1 - jb; if (ecnt > EC4) ecnt = EC4;
    __syncthreads();   // Y ready (1st iter) / staging reuse safe (later iters)
    // B1: parallel descriptor staging (2 latency round-trips total)
    if (tid < ecnt) {
      int e = ess[jb + tid];
      int r2 = ei[e] >> 1;
      nll[tid] = r2 & (TSN - 1);
      dpl[tid] = dpos[e];
      axl[tid] = cart[2 * e] * inv + 0.5f;
      ayl[tid] = cart[2 * e + 1] * inv + 0.5f;
    }
    __syncthreads();
    // B2: cooperative t-matrix fill (kills 64-lane-redundant tk math)
    for (int idx = tid; idx < ecnt * 32; idx += 256) {
      int j = idx >> 5, k = idx & 31;
      if (k < 25)
        tl[j][k] = fmaxf(axl[j] * w2a_l[k] + ayl[j] * w2a_l[25 + k] + b2a_l[k], 0.f);
    }
    __syncthreads();
    // B3: per-edge contraction; 4 independent acc chains, conflict-free LDS
    for (int j = w; j < ecnt; j += 4) {
      const float* Yp = &Y[nll[j]][0][0];
      const float* tp = tl[j];
      float acc0 = Yp[25 * 64 + o], acc1 = 0.f, acc2 = 0.f, acc3 = 0.f;
#pragma unroll
      for (int k = 0; k < 24; k += 4) {
        acc0 += tp[k]     * Yp[k * 64 + o];
        acc1 += tp[k + 1] * Yp[(k + 1) * 64 + o];
        acc2 += tp[k + 2] * Yp[(k + 2) * 64 + o];
        acc3 += tp[k + 3] * Yp[(k + 3) * 64 + o];
      }
      acc0 += tp[24] * Yp[24 * 64 + o];
      msg[(size_t)dpl[j] * 64 + o] = (acc0 + acc1) + (acc2 + acc3);
    }
  }
}

// ---------------- conv2 pass B: per-dest contiguous gather + mean + root2 + bias2 + elu
template <typename T>
__global__ __launch_bounds__(256) void k5_gather(
    const int* __restrict__ flag,
    const float* __restrict__ msg, const int* __restrict__ off2,
    const float* __restrict__ x2,
    const T* __restrict__ root2, const T* __restrict__ bias2,
    float* __restrict__ h2) {
  if (flag[0] != want_flag<T>()) return;
  __shared__ float r2_l[2048];   // [i*64+o]
  __shared__ float b2_l[64];
  int tid = threadIdx.x;
  for (int j = tid; j < 2048; j += 256) r2_l[j] = lo(root2, j);
  if (tid < 64) b2_l[tid] = lo(bias2, tid);
  __syncthreads();
  int d = blockIdx.x * 4 + (tid >> 6);
  int o = tid & 63;
  int j0 = off2[d], j1 = off2[d + 1];
  float s0 = 0.f, s1 = 0.f;
  int j = j0;
  for (; j + 1 < j1; j += 2) {
    s0 += msg[(size_t)j * 64 + o];
    s1 += msg[(size_t)(j + 1) * 64 + o];
  }
  if (j < j1) s0 += msg[(size_t)j * 64 + o];
  float c = fmaxf((float)(j1 - j0), 1.f);
  float r = b2_l[o];
  const float* xr = x2 + d * 32;
#pragma unroll 8
  for (int i = 0; i < 32; ++i) r += xr[i] * r2_l[i * 64 + o];
  h2[d * 64 + o] = elu((s0 + s1) / c + r);
}

// ---------------- pair max-pool 2 + per-graph segmented sum
#define K6CH 16
__global__ __launch_bounds__(256) void k6_pool2(
    const float* __restrict__ h2, const int* __restrict__ batch,
    float* __restrict__ gsum, float* __restrict__ gcnt) {
  int wid = blockIdx.x * 4 + (threadIdx.x >> 6);
  int lane = threadIdx.x & 63;
  int m0 = wid * K6CH;
  if (m0 >= N3) return;
  int m1 = m0 + K6CH < N3 ? m0 + K6CH : N3;
  int bcur = batch[4 * m0];
  float acc = 0.f, cnt = 0.f;
  for (int m = m0; m < m1; ++m) {
    int b = batch[4 * m];
    float v = fmaxf(h2[(2 * m) * 64 + lane], h2[(2 * m + 1) * 64 + lane]);
    if (b != bcur) {
      atomicAdd(gsum + bcur * 64 + lane, acc);
      if (lane == 0) atomicAdd(gcnt + bcur, cnt);
      acc = 0.f; cnt = 0.f; bcur = b;
    }
    acc += v; cnt += 1.f;
  }
  atomicAdd(gsum + bcur * 64 + lane, acc);
  if (lane == 0) atomicAdd(gcnt + bcur, cnt);
}

// ---------------- graph mean -> fc1 -> elu -> fc2 -> log_softmax
template <typename T>
__global__ __launch_bounds__(128) void k7_head(
    const int* __restrict__ flag,
    const float* __restrict__ gsum, const float* __restrict__ gcnt,
    const T* __restrict__ fc1_w, const T* __restrict__ fc1_b,
    const T* __restrict__ fc2_w, const T* __restrict__ fc2_b,
    T* __restrict__ out) {
  if (flag[0] != want_flag<T>()) return;
  __shared__ float gv[64];
  __shared__ float h1s[128];
  __shared__ float zs[NC];
  __shared__ float lse;
  int g = blockIdx.x, tid = threadIdx.x;
  if (tid < 64) gv[tid] = gsum[g * 64 + tid] / fmaxf(gcnt[g], 1.f);
  __syncthreads();
  float a = lo(fc1_b, tid);
#pragma unroll 8
  for (int o = 0; o < 64; ++o) a += gv[o] * lo(fc1_w, o * 128 + tid);
  h1s[tid] = elu(a);
  __syncthreads();
  if (tid < NC) {
    float s = lo(fc2_b, tid);
    for (int j = 0; j < 128; ++j) s += h1s[j] * lo(fc2_w, j * NC + tid);
    zs[tid] = s;
  }
  __syncthreads();
  if (tid == 0) {
    float m = -1e30f;
    for (int c = 0; c < NC; ++c) m = fmaxf(m, zs[c]);
    float s = 0.f;
    for (int c = 0; c < NC; ++c) s += expf(zs[c] - m);
    lse = m + logf(s);
  }
  __syncthreads();
  if (tid < NC) sto(out, g * NC + tid, zs[tid] - lse);
}

template <typename T>
static void run_conv1(void* const* d_in, float* ws, hipStream_t stream) {
  const int* ei   = (const int*)d_in[19];
  const int* flag = (const int*)(ws + FLAG_OFF);
  k1_blk<T><<<NBLK1, 256, 0, stream>>>(
      flag, (const T*)d_in[0], (const T*)d_in[1], (const T*)d_in[2], ei,
      (const T*)d_in[3], (const T*)d_in[4], (const T*)d_in[5], (const T*)d_in[6],
      (const T*)d_in[7], (const T*)d_in[8],
      (const int*)(ws + OFF1_OFF), (const int*)(ws + ES1_OFF),
      ws + X2_OFF, ws + P2_OFF);
}

template <typename T>
static void run_conv2(void* const* d_in, float* ws, hipStream_t stream) {
  const int* ei   = (const int*)d_in[19];
  const int* flag = (const int*)(ws + FLAG_OFF);
  k4_src<T><<<NTS, 256, 0, stream>>>(
      flag, ei, ws + CT_OFF, ws + MV_OFF, ws + X2_OFF,
      (const T*)d_in[9], (const T*)d_in[10], (const T*)d_in[11], (const T*)d_in[12],
      (const int*)(ws + OFFS_OFF), (const int*)(ws + ESS_OFF),
      (const int*)(ws + DPOS_OFF), ws + MSG_OFF);
  k5_gather<T><<<N2 / 4, 256, 0, stream>>>(
      flag, ws + MSG_OFF, (const int*)(ws + OFF2_OFF), ws + X2_OFF,
      (const T*)d_in[13], (const T*)d_in[14], ws + H2_OFF);
}

extern "C" void kernel_launch(void* const* d_in, const int* in_sizes, int n_in,
                              void* d_out, int out_size, void* d_ws, size_t ws_size,
                              hipStream_t stream) {
  float* ws = (float*)d_ws;
  const int* flag = (const int*)(ws + FLAG_OFF);
  const int* ei = (const int*)d_in[19];
  const int* batch = (const int*)d_in[20];

  k0_detect<<<1, 256, 0, stream>>>(d_in[0], d_in[1], (int*)(ws + FLAG_OFF));
  hipMemsetAsync(d_ws, 0, (size_t)ZERO_FLOATS * 4, stream);

  // per-node CSR builds (dtype-free): histogram -> hierarchical scan -> placement
  kc_deg<<<(N_EDGES + 255) / 256, 256, 0, stream>>>(
      ei, (int*)(ws + DEG1_OFF), (int*)(ws + DEG2_OFF), (int*)(ws + DEGS_OFF));
  ks_scanA<<<SC_CT, 256, 0, stream>>>(
      (const int*)(ws + DEG1_OFF), (const int*)(ws + DEG2_OFF), (const int*)(ws + DEGS_OFF),
      (int*)(ws + OFF1_OFF), (int*)(ws + OFF2_OFF), (int*)(ws + OFFS_OFF),
      (int*)(ws + BSUM_OFF));
  ks_scanB<<<3, 256, 0, stream>>>((int*)(ws + BSUM_OFF));
  ks_scanC<<<SC_CT, 256, 0, stream>>>(
      (int*)(ws + OFF1_OFF), (int*)(ws + OFF2_OFF), (int*)(ws + OFFS_OFF),
      (int*)(ws + CUR1_OFF), (int*)(ws + CUR2_OFF), (int*)(ws + CURS_OFF),
      (const int*)(ws + BSUM_OFF));
  kc_place<<<(N_EDGES + 255) / 256, 256, 0, stream>>>(
      ei, (int*)(ws + CUR1_OFF), (int*)(ws + ES1_OFF),
      (int*)(ws + CUR2_OFF), (int*)(ws + DPOS_OFF),
      (int*)(ws + CURS_OFF), (int*)(ws + ESS_OFF));

  // conv1 + pool1 (both dtype variants; non-matching early-returns)
  run_conv1<float>(d_in, ws, stream);
  run_conv1<bf16>(d_in, ws, stream);

  // cart/maxv (dtype-free, needs pos2)
  k3_cart<<<(N_EDGES + 255) / 256, 256, 0, stream>>>(
      ei, ws + P2_OFF, ws + CT_OFF, (unsigned int*)(ws + MV_OFF));

  // conv2: factorized messages (pass A) + contiguous gather (pass B)
  run_conv2<float>(d_in, ws, stream);
  run_conv2<bf16>(d_in, ws, stream);

  // pool2 + head
  k6_pool2<<<(N3 / K6CH + 4) / 4, 256, 0, stream>>>(
      ws + H2_OFF, batch, ws + GS_OFF, ws + GC_OFF);
  k7_head<float><<<NGRAPH, 128, 0, stream>>>(
      flag, ws + GS_OFF, ws + GC_OFF,
      (const float*)d_in[15], (const float*)d_in[16],
      (const float*)d_in[17], (const float*)d_in[18], (float*)d_out);
  k7_head<bf16><<<NGRAPH, 128, 0, stream>>>(
      flag, ws + GS_OFF, ws + GC_OFF,
      (const bf16*)d_in[15], (const bf16*)d_in[16],
      (const bf16*)d_in[17], (const bf16*)d_in[18], (bf16*)d_out);
}